// Round 1
// baseline (1445.561 us; speedup 1.0000x reference)
//
#include <hip/hip_runtime.h>

typedef unsigned short u16;
typedef unsigned int u32;
typedef __attribute__((ext_vector_type(8))) short short8;
typedef __attribute__((ext_vector_type(4))) float f32x4;

constexpr int CB = 64, CT = 512, CX = 8, CH = 128;

__device__ __forceinline__ u16 f2b(float f) {
  u32 u = __float_as_uint(f);
  return (u16)((u + 0x7FFFu + ((u >> 16) & 1u)) >> 16);  // RNE bf16
}
__device__ __forceinline__ float sigf(float x) {
  return __fdividef(1.0f, 1.0f + __expf(-x));
}
__device__ __forceinline__ float tanhfast(float x) {
  return 1.0f - __fdividef(2.0f, __expf(2.0f * x) + 1.0f);
}
__device__ __forceinline__ f32x4 mfma16(short8 a, short8 b, f32x4 c) {
  return __builtin_amdgcn_mfma_f32_16x16x32_bf16(a, b, c, 0, 0, 0);
}

// ---------------- ws layout (bytes) ----------------
// 0        : WgwT  bf16 [384][256]  B^T of [w_hh_w; w_ih_w]   (196608 B)
// 196608   : WahcT bf16 [512][128]  B^T of [a_hh | w_hh_c]    (131072 B)
// 327680   : WcaT  bf16 [512][128]  B^T of [w_ih_c | a_ih]    (131072 B)
// 458752   : wica  f32  [B*T][512]  [wi_c_all | a_wi_all]     (67108864 B)

__global__ void prep_kernel(const float* __restrict__ w_ih_c, const float* __restrict__ w_hh_c,
                            const float* __restrict__ a_ih, const float* __restrict__ a_hh,
                            const float* __restrict__ w_ih_w, const float* __restrict__ w_hh_w,
                            u16* __restrict__ WgwT, u16* __restrict__ WahcT, u16* __restrict__ WcaT) {
  int gid = blockIdx.x * blockDim.x + threadIdx.x;  // 224*1024 = 229376
  if (gid < 98304) {                 // WgwT[n][k], n<384, k<256
    int n = gid >> 8, k = gid & 255;
    float v = (k < 128) ? w_hh_w[k * 384 + n] : w_ih_w[(k - 128) * 384 + n];
    WgwT[gid] = f2b(v);
  } else if (gid < 163840) {         // WahcT[n][k], n<512, k<128
    int i = gid - 98304; int n = i >> 7, k = i & 127;
    float v = (n < 128) ? a_hh[k * 128 + n] : w_hh_c[k * 384 + (n - 128)];
    WahcT[i] = f2b(v);
  } else if (gid < 229376) {         // WcaT[n][k], n<512, k<128
    int i = gid - 163840; int n = i >> 7, k = i & 127;
    float v = (n < 384) ? w_ih_c[k * 384 + n] : a_ih[k * 128 + (n - 384)];
    WcaT[i] = f2b(v);
  }
}

// wica[m][n] = sum_k inp[m][k]*Wca[k][n] + bias, m = b*T+t, N=512, K=128
__global__ __launch_bounds__(256) void proj_kernel(const float* __restrict__ inp,
    const u16* __restrict__ WcaT, const float* __restrict__ bias_c,
    const float* __restrict__ a_bias, float* __restrict__ wica) {
  const int m0 = blockIdx.x * 64;
  const int wv = threadIdx.x >> 6, ln = threadIdx.x & 63;
  const int l16 = ln & 15, qd = ln >> 4;
  const int arow = m0 + wv * 16 + l16;
  short8 af[4];
#pragma unroll
  for (int kt = 0; kt < 4; ++kt) {
    const float* p = inp + (size_t)arow * 128 + kt * 32 + qd * 8;
    float4 x0 = *(const float4*)p;
    float4 x1 = *(const float4*)(p + 4);
    short8 a;
    a[0] = (short)f2b(x0.x); a[1] = (short)f2b(x0.y); a[2] = (short)f2b(x0.z); a[3] = (short)f2b(x0.w);
    a[4] = (short)f2b(x1.x); a[5] = (short)f2b(x1.y); a[6] = (short)f2b(x1.z); a[7] = (short)f2b(x1.w);
    af[kt] = a;
  }
  for (int nt = 0; nt < 32; ++nt) {
    const int col = nt * 16 + l16;
    f32x4 acc = {0.f, 0.f, 0.f, 0.f};
#pragma unroll
    for (int kt = 0; kt < 4; ++kt) {
      short8 bf = *(const short8*)(WcaT + (size_t)col * 128 + kt * 32 + qd * 8);
      acc = mfma16(af[kt], bf, acc);
    }
    const float bias = (col < 384) ? bias_c[col] : a_bias[col - 384];
#pragma unroll
    for (int r = 0; r < 4; ++r) {
      const int orow = m0 + wv * 16 + qd * 4 + r;
      wica[(size_t)orow * 512 + col] = acc[r] + bias;
    }
  }
}

__global__ __launch_bounds__(512, 2) void scan_kernel(
    const float* __restrict__ skip_words,  // [B][T][X][128]
    const int* __restrict__ srcp,          // [B][T][X]
    const int* __restrict__ cntp,          // [B][T]
    const float* __restrict__ bias_w,      // [384]
    const u16* __restrict__ WgwT,          // [384][256]
    const u16* __restrict__ WahcT,         // [512][128]
    const float* __restrict__ wica,        // [B*T][512]
    float* __restrict__ out)               // hs [B][T][128] ; cs follows
{
  const int b = blockIdx.x;
  const int tid = threadIdx.x;
  const int wv = tid >> 6;
  const int ln = tid & 63;
  const int l16 = ln & 15;
  const int qd = ln >> 4;
  const int h = wv * 16 + l16;

  float* hs = out + (size_t)b * CT * CH;
  float* cs = out + (size_t)(CB + b) * CT * CH;
  const float* swb = skip_words + (size_t)b * CT * CX * CH;
  const int* srcb = srcp + b * CT * CX;
  const int* cntb = cntp + b * CT;
  const float* wicab = wica + (size_t)b * CT * 512;

  // LDS (padded strides 264 / 136 to break power-of-2 bank aliasing)
  __shared__ __align__(16) u16 Asg[16 * 264];   // A for gw: rows=slots, k=[h_x|sw]
  __shared__ __align__(16) u16 Psg[16 * 136];   // A for alpha/gc: rows 0..7 c1_skip, row 8 h0
  __shared__ __align__(16) float Csg[8 * 128];  // gathered c_x (fp32)
  __shared__ __align__(16) u16 hprev[128];      // bf16 of h_{t}
  __shared__ __align__(16) float cprev[128];    // fp32 of c_{t}
  __shared__ float gca[512];                    // [0,384): wi_c ; [384,512): a_wi

  for (int i = tid; i < 16 * 264; i += 512) Asg[i] = 0;
  for (int i = tid; i < 16 * 136; i += 512) Psg[i] = 0;
  if (tid < 128) { hprev[tid] = 0; cprev[tid] = 0.0f; }

  // persistent B-fragments (bf16) ------------------------------------------
  short8 wgwf[3][8];  // gate g in {f,i,g}: ntile 8g+wv  (col = g*128 + h)
#pragma unroll
  for (int g = 0; g < 3; ++g) {
    const int n = g * 128 + h;
#pragma unroll
    for (int kt = 0; kt < 8; ++kt)
      wgwf[g][kt] = *(const short8*)(WgwT + (size_t)n * 256 + kt * 32 + qd * 8);
  }
  short8 wacf[4][4];  // j=0: a_hh col h ; j=1..3: w_hh_c gate cols (j-1)*128+h
#pragma unroll
  for (int j = 0; j < 4; ++j) {
    const int n = j * 128 + h;
#pragma unroll
    for (int kt = 0; kt < 4; ++kt)
      wacf[j][kt] = *(const short8*)(WahcT + (size_t)n * 128 + kt * 32 + qd * 8);
  }
  const float bw0 = bias_w[h], bw1 = bias_w[128 + h], bw2 = bias_w[256 + h];

  // pipeline preload for t=0 (src/cnt also for t=1) -------------------------
  int src_c = srcb[wv];
  int cnt_c = cntb[0];
  int src_n = srcb[CX + wv];
  int cnt_n = cntb[1];
  float2 h2c, c2c, sw2c;
  h2c = *(const float2*)(hs + (size_t)src_c * CH + 2 * ln);   // poison at t=0, masked
  c2c = *(const float2*)(cs + (size_t)src_c * CH + 2 * ln);
  sw2c = *(const float2*)(swb + (size_t)wv * CH + 2 * ln);
  float wicac = wicab[tid];
  float2 h2n = {0.f, 0.f}, c2n = {0.f, 0.f}, sw2n = {0.f, 0.f};
  float wican = 0.f;
  int src_n2 = 0, cnt_n2 = 0;
  __syncthreads();  // LDS init visible

  for (int t = 0; t < CT; ++t) {
    // ---- stage 1: stage A-matrix, c_x, wi parts --------------------------
    const bool fresh = (src_c == t - 1);  // wave-uniform
    if (fresh) {
      *(u32*)&Asg[wv * 264 + 2 * ln] = *(const u32*)&hprev[2 * ln];
      *(float2*)&Csg[wv * 128 + 2 * ln] = *(const float2*)&cprev[2 * ln];
    } else {
      *(u32*)&Asg[wv * 264 + 2 * ln] = (u32)f2b(h2c.x) | ((u32)f2b(h2c.y) << 16);
      *(float2*)&Csg[wv * 128 + 2 * ln] = c2c;
    }
    *(u32*)&Asg[wv * 264 + 128 + 2 * ln] = (u32)f2b(sw2c.x) | ((u32)f2b(sw2c.y) << 16);
    gca[tid] = wicac;
    if (wv == 7)  // Psg row 8 = h0 (= h_{t})
      *(u32*)&Psg[8 * 136 + 2 * ln] = *(const u32*)&hprev[2 * ln];
    __syncthreads();  // barrier A

    // ---- stage 2: prefetch for t+1 (overlaps with MFMA below) ------------
    if (t + 1 < CT) {
      if (src_n != t) {  // not-fresh gather: rows written <= t-1, safe
        h2n = *(const float2*)(hs + (size_t)src_n * CH + 2 * ln);
        c2n = *(const float2*)(cs + (size_t)src_n * CH + 2 * ln);
      }
      sw2n = *(const float2*)(swb + ((size_t)(t + 1) * CX + wv) * CH + 2 * ln);
      wican = wicab[(size_t)(t + 1) * 512 + tid];
      if (t + 2 < CT) { src_n2 = srcb[(t + 2) * CX + wv]; cnt_n2 = cntb[t + 2]; }
    }

    // ---- stage 3: gw = [h_x|sw] @ [w_hh_w;w_ih_w], c1_skip ---------------
    f32x4 d0 = {0.f, 0.f, 0.f, 0.f}, d1 = d0, d2 = d0;
#pragma unroll
    for (int kt = 0; kt < 8; ++kt) {
      short8 a = *(const short8*)&Asg[l16 * 264 + kt * 32 + qd * 8];
      d0 = mfma16(a, wgwf[0][kt], d0);
      d1 = mfma16(a, wgwf[1][kt], d1);
      d2 = mfma16(a, wgwf[2][kt], d2);
    }
    float c1s[4] = {0.f, 0.f, 0.f, 0.f};
    if (qd < 2) {  // rows 0..7 = real slots
#pragma unroll
      for (int r = 0; r < 4; ++r) {
        const int row = qd * 4 + r;
        const float cx = Csg[row * 128 + h];
        const float fg = sigf(d0[r] + bw0);
        const float ig = sigf(d1[r] + bw1);
        const float gg = tanhfast(d2[r] + bw2);
        const float v = fg * cx + ig * gg;
        c1s[r] = v;
        Psg[row * 136 + h] = f2b(v);
      }
    }
    __syncthreads();  // barrier B

    // ---- stage 5: [c1_skip;h0] @ [a_hh|w_hh_c], softmax-combine ----------
    f32x4 e0 = {0.f, 0.f, 0.f, 0.f}, e1 = e0, e2 = e0, e3 = e0;
#pragma unroll
    for (int kt = 0; kt < 4; ++kt) {
      short8 a = *(const short8*)&Psg[l16 * 136 + kt * 32 + qd * 8];
      e0 = mfma16(a, wacf[0][kt], e0);
      e1 = mfma16(a, wacf[1][kt], e1);
      e2 = mfma16(a, wacf[2][kt], e2);
      e3 = mfma16(a, wacf[3][kt], e3);
    }
    // gc row (D row 8 = qd 2, reg 0) lives at lane 32+l16 of this wave
    const float gi_d = __shfl(e1[0], 32 + l16, 64);
    const float go_d = __shfl(e2[0], 32 + l16, 64);
    const float gg_d = __shfl(e3[0], 32 + l16, 64);
    const float awi = gca[384 + h];
    const float i_g = sigf(gi_d + gca[h]);
    const float o_g = sigf(go_d + gca[128 + h]);
    const float g_g = tanhfast(gg_d + gca[256 + h]);
    float pe = 0.0f, pec = 0.0f;
#pragma unroll
    for (int r = 0; r < 4; ++r) {
      const int row = qd * 4 + r;
      if (row < cnt_c) {  // rows >= cnt masked (exp -> 0); rows 8..15 always
        const float al = sigf(e0[r] + awi);
        const float e = __expf(al);
        pe += e;
        pec += e * c1s[r];
      }
    }
    pe += __shfl_xor(pe, 16, 64);  pec += __shfl_xor(pec, 16, 64);
    pe += __shfl_xor(pe, 32, 64);  pec += __shfl_xor(pec, 32, 64);
    const float ei = __expf(i_g);
    const float c1 = __fdividef(ei * g_g + pec, ei + pe);
    const float h1 = o_g * tanhfast(c1);

    // ---- stage 6: epilogue ----------------------------------------------
    if (qd == 0) {
      hs[(size_t)t * CH + h] = h1;
      cs[(size_t)t * CH + h] = c1;
      hprev[h] = f2b(h1);
      cprev[h] = c1;
    }
    __syncthreads();  // barrier C: drains stores, publishes hprev/cprev

    // rotate pipeline
    h2c = h2n; c2c = c2n; sw2c = sw2n; wicac = wican;
    src_c = src_n; cnt_c = cnt_n; src_n = src_n2; cnt_n = cnt_n2;
  }
}

extern "C" void kernel_launch(void* const* d_in, const int* in_sizes, int n_in,
                              void* d_out, int out_size, void* d_ws, size_t ws_size,
                              hipStream_t stream) {
  (void)in_sizes; (void)n_in; (void)out_size; (void)ws_size;
  const float* inp    = (const float*)d_in[0];
  const float* skw    = (const float*)d_in[1];
  const int*   ssrc   = (const int*)d_in[3];
  const int*   scnt   = (const int*)d_in[4];
  const float* w_ih_c = (const float*)d_in[5];
  const float* w_hh_c = (const float*)d_in[6];
  const float* bias_c = (const float*)d_in[7];
  const float* a_ih   = (const float*)d_in[8];
  const float* a_hh   = (const float*)d_in[9];
  const float* a_bias = (const float*)d_in[10];
  const float* w_ih_w = (const float*)d_in[11];
  const float* w_hh_w = (const float*)d_in[12];
  const float* bias_w = (const float*)d_in[13];

  char* ws = (char*)d_ws;
  u16*   WgwT  = (u16*)(ws);
  u16*   WahcT = (u16*)(ws + 196608);
  u16*   WcaT  = (u16*)(ws + 327680);
  float* wica  = (float*)(ws + 458752);
  float* out   = (float*)d_out;

  prep_kernel<<<224, 1024, 0, stream>>>(w_ih_c, w_hh_c, a_ih, a_hh, w_ih_w, w_hh_w,
                                        WgwT, WahcT, WcaT);
  proj_kernel<<<512, 256, 0, stream>>>(inp, WcaT, bias_c, a_bias, wica);
  scan_kernel<<<64, 512, 0, stream>>>(skw, ssrc, scnt, bias_w, WgwT, WahcT, wica, out);
}